// Round 2
// baseline (150.412 us; speedup 1.0000x reference)
//
#include <hip/hip_runtime.h>
#include <cstdint>
#include <cstddef>

#define MROWS 1024
#define NCOLS 4096
#define TOPK 8

typedef unsigned long long u64;
typedef unsigned int u32;

// Order-preserving float->u32 map (total order, matches score order exactly).
__device__ inline u32 fkey(u32 b) { return (b & 0x80000000u) ? ~b : (b | 0x80000000u); }

// key = (ord << 22) | ((1023-row) << 12) | (4095-col)   (54 bits used)
__device__ inline int key_col(u64 k) { return (NCOLS - 1) - (int)(k & 0xFFFull); }
__device__ inline int key_row(u64 k) { return (MROWS - 1) - (int)((k >> 12) & 0x3FFull); }

// single-wave LDS ordering fence: wait LDS only, do NOT drain vmcnt
#define WAVE_FENCE() __asm__ volatile("s_waitcnt lgkmcnt(0)" ::: "memory")

__device__ inline float wave_sum_f(float v) {
    #pragma unroll
    for (int off = 32; off >= 1; off >>= 1)
        v += __shfl_xor(v, off, 64);
    return v;
}
__device__ inline u64 wave_max_u64(u64 v) {
    #pragma unroll
    for (int off = 32; off >= 1; off >>= 1) {
        u64 o = __shfl_xor(v, off, 64);
        v = o > v ? o : v;
    }
    return v;
}
__device__ inline u64 umax64(u64 a, u64 b) { return a > b ? a : b; }

// wave max over distinct 54-bit keys: butterfly on high-32 only, then resolve
// the (wave-uniform, rare) high-word tie on the low 32 bits.
__device__ inline u64 wave_max_key(u64 v) {
    u32 h = (u32)(v >> 32);
    u32 hm = h;
    #pragma unroll
    for (int off = 32; off >= 1; off >>= 1) {
        u32 o = __shfl_xor(hm, off, 64);
        hm = o > hm ? o : hm;
    }
    u64 tie = __ballot(h == hm);
    if ((tie & (tie - 1ull)) == 0ull) {          // unique high word (common path)
        int src = __ffsll((long long)tie) - 1;
        return __shfl(v, src, 64);
    }
    u32 l = (h == hm) ? (u32)v : 0u;
    #pragma unroll
    for (int off = 32; off >= 1; off >>= 1) {
        u32 o = __shfl_xor(l, off, 64);
        l = o > l ? o : l;
    }
    return ((u64)hm << 32) | l;
}

// ---------------- K1: per-row top-8 score-keys + exp-sum + bitmap --------------
// __expf(s)/sum(__expf(s)) == softmax(s) to ~1e-6 rel (s ~ N(0,1)); the
// uniform scale cannot reorder values, so score order == policy order.
__global__ __launch_bounds__(256) void k_prep(const float* __restrict__ s,
                                              const int* __restrict__ cont,
                                              const int* __restrict__ prev,
                                              float* __restrict__ rowsum,
                                              unsigned* __restrict__ bitmap_g,
                                              u64* __restrict__ outkeys) {
    __shared__ unsigned lbm[NCOLS / 32];   // 128: consumed-column bitmap (local)
    __shared__ u64 wavecand[4 * TOPK];
    __shared__ float fred[4];
    int r = blockIdx.x, t = threadIdx.x;
    int wid = t >> 6, lane = t & 63;

    // issue the row loads FIRST: they fly while the bitmap phase runs
    const float4* s4 = (const float4*)(s + (size_t)r * NCOLS);
    float4 vv[4];
    vv[0] = s4[t];
    vv[1] = s4[t + 256];
    vv[2] = s4[t + 512];
    vv[3] = s4[t + 768];

    if (t < 128) lbm[t] = 0u;
    __syncthreads();
    for (int i = t; i < MROWS; i += 256) {
        if (cont[i]) {
            int c = prev[i];
            atomicOr(&lbm[c >> 5], 1u << (c & 31));
        }
    }
    __syncthreads();
    if (r == 0 && t < 128) bitmap_g[t] = lbm[t];   // export for K2's match block

    int cg_ = cont[r];
    u64 rowpart = (u64)(MROWS - 1 - r) << 12;
    u64 mykeys[16];
    float acc = 0.0f;
    #pragma unroll
    for (int i = 0; i < 4; ++i) {
        float4 v = vv[i];
        acc += __expf(v.x) + __expf(v.y) + __expf(v.z) + __expf(v.w);
        int f = t + i * 256;
        int c0 = 4 * f;
        unsigned bmw = lbm[c0 >> 5];
        float se[4] = {v.x, v.y, v.z, v.w};
        #pragma unroll
        for (int e = 0; e < 4; ++e) {
            int c = c0 + e;
            u64 kk = 0ull;
            if (!cg_ && !((bmw >> (c & 31)) & 1u))
                kk = ((u64)fkey(__float_as_uint(se[e])) << 22) | rowpart |
                     (u64)(NCOLS - 1 - c);
            mykeys[i * 4 + e] = kk;
        }
    }
    // per-row exp-sum partial
    acc = wave_sum_f(acc);
    if (lane == 0) fred[wid] = acc;
    __syncthreads();
    if (t == 0) rowsum[r] = fred[0] + fred[1] + fred[2] + fred[3];

    // per-wave top-8 (keys distinct -> unique winner each pass)
    u64 tmax = 0ull;
    #pragma unroll
    for (int k = 0; k < 16; ++k) tmax = umax64(tmax, mykeys[k]);
    for (int pass = 0; pass < TOPK; ++pass) {
        u64 w = wave_max_key(tmax);
        if (lane == 0) wavecand[wid * TOPK + pass] = w;
        if (tmax == w && w != 0ull) {
            #pragma unroll
            for (int k = 0; k < 16; ++k)
                if (mykeys[k] == w) mykeys[k] = 0ull;
            tmax = 0ull;
            #pragma unroll
            for (int k = 0; k < 16; ++k) tmax = umax64(tmax, mykeys[k]);
        }
    }
    __syncthreads();
    // wave 0 merges the 32 candidates -> true row top-8
    if (wid == 0) {
        u64 val = (lane < 32) ? wavecand[lane] : 0ull;
        for (int pass = 0; pass < TOPK; ++pass) {
            u64 g = wave_max_key(val);
            if (lane == 0) outkeys[(size_t)r * TOPK + pass] = g;   // 0 for cg_ rows
            if (val == g && g != 0ull) val = 0ull;
        }
    }
}

// ---------------- K2: block 0 = single-wave match; blocks 1..1024 = policy -----
// Match: dominant-edge commit (row-best == col-best among surviving keys),
// identical to serial greedy since keys are distinct. ONE WAVE owns all 1024
// rows (16/lane) -> every round barrier is a free s_waitcnt lgkmcnt(0) instead
// of a 16-wave __syncthreads. Keys re-read from global (64 KB, L2-hot) with
// per-lane register alive-masks; colbest entries tagged (round << 54) so stale
// rounds auto-lose.
__global__ __launch_bounds__(256) void k_policy_match(const float* __restrict__ s,
                                                      const int* __restrict__ cont,
                                                      const int* __restrict__ prev,
                                                      const float* __restrict__ rowsum,
                                                      const unsigned* __restrict__ bitmap,
                                                      const u64* __restrict__ keys_g,
                                                      float* __restrict__ policy,
                                                      float* __restrict__ actions) {
    __shared__ u64 colbest[NCOLS];             // 32 KiB (match only)
    __shared__ unsigned coldone[NCOLS / 32];   // 128
    __shared__ unsigned rowdone[MROWS / 32];   // 32
    __shared__ float act[MROWS];               // 4 KiB
    __shared__ float fredf[4];

    int t = threadIdx.x;

    if (blockIdx.x != 0) {
        // ---------------- policy row write (256 thr, 4 float4/thr) ------------
        int r = blockIdx.x - 1;
        const float4* srow4 = (const float4*)(s + (size_t)r * NCOLS);
        // issue row loads first; they fly during the rowsum reduce
        float4 w0 = srow4[t], w1 = srow4[t + 256], w2 = srow4[t + 512], w3 = srow4[t + 768];
        float sv = rowsum[t] + rowsum[t + 256] + rowsum[t + 512] + rowsum[t + 768];
        sv = wave_sum_f(sv);
        int wid = t >> 6, lane = t & 63;
        if (lane == 0) fredf[wid] = sv;
        __syncthreads();
        float inv = 1.0f / (fredf[0] + fredf[1] + fredf[2] + fredf[3]);
        float4* prow4 = (float4*)(policy + (size_t)r * NCOLS);
        float4 p;
        p.x = __expf(w0.x) * inv; p.y = __expf(w0.y) * inv;
        p.z = __expf(w0.z) * inv; p.w = __expf(w0.w) * inv;
        prow4[t] = p;
        p.x = __expf(w1.x) * inv; p.y = __expf(w1.y) * inv;
        p.z = __expf(w1.z) * inv; p.w = __expf(w1.w) * inv;
        prow4[t + 256] = p;
        p.x = __expf(w2.x) * inv; p.y = __expf(w2.y) * inv;
        p.z = __expf(w2.z) * inv; p.w = __expf(w2.w) * inv;
        prow4[t + 512] = p;
        p.x = __expf(w3.x) * inv; p.y = __expf(w3.y) * inv;
        p.z = __expf(w3.z) * inv; p.w = __expf(w3.w) * inv;
        prow4[t + 768] = p;
        return;
    }

    // ---------------- match: block 0, wave 0 only --------------------------
    if (t >= 64) return;
    int lane = t;

    #pragma unroll
    for (int i = 0; i < NCOLS / 64; ++i) colbest[lane + i * 64] = 0ull;
    coldone[lane] = bitmap[lane];
    coldone[lane + 64] = bitmap[lane + 64];
    if (lane < 32) rowdone[lane] = 0u;
    WAVE_FENCE();

    // lane owns rows lane*16 .. lane*16+15
    u32 rowact = 0u;
    u64 kal0 = 0ull, kal1 = 0ull;   // 8-bit key-alive mask per row
    #pragma unroll
    for (int j = 0; j < 16; ++j) {
        int r = lane * 16 + j;
        int cg = cont[r];
        act[r] = cg ? (float)prev[r] : -1.0f;
        if (cg) {
            atomicOr(&rowdone[r >> 5], 1u << (r & 31));
        } else {
            rowact |= (1u << j);
            if (j < 8) kal0 |= (0xFFull << (8 * j));
            else       kal1 |= (0xFFull << (8 * (j - 8)));
        }
    }
    WAVE_FENCE();

    bool exh_l = false;
    const u64* gk = keys_g + (size_t)lane * (16 * TOPK);
    u64 bestv[16];
    #pragma unroll
    for (int j = 0; j < 16; ++j) bestv[j] = 0ull;

    for (int round = 1; round < 1100; ++round) {
        u64 tag = (u64)round << 54;
        // ---- scan + submit ----
        #pragma unroll
        for (int j = 0; j < 16; ++j) {
            if (!(rowact & (1u << j))) continue;
            u32 al = (u32)(((j < 8 ? kal0 : kal1) >> (8 * (j & 7))) & 0xFFull);
            u32 nal = al;
            u64 best = 0ull;
            #pragma unroll
            for (int k = 0; k < TOPK; ++k) {
                if (!(al & (1u << k))) continue;
                u64 kk = gk[j * TOPK + k];
                if (kk == 0ull) { nal &= ~(1u << k); continue; }
                int c = key_col(kk);
                if ((coldone[c >> 5] >> (c & 31)) & 1u) { nal &= ~(1u << k); continue; }
                atomicMax((u64*)&colbest[c], tag | kk);
                best = umax64(best, kk);
            }
            if (j < 8) kal0 = (kal0 & ~(0xFFull << (8 * j))) | ((u64)nal << (8 * j));
            else       kal1 = (kal1 & ~(0xFFull << (8 * (j - 8)))) | ((u64)nal << (8 * (j - 8)));
            if (nal == 0u) { rowact &= ~(1u << j); exh_l = true; bestv[j] = 0ull; }
            else bestv[j] = best;
        }
        WAVE_FENCE();          // submissions visible
        // ---- commit ----
        #pragma unroll
        for (int j = 0; j < 16; ++j) {
            if (!(rowact & (1u << j)) || bestv[j] == 0ull) continue;
            int c = key_col(bestv[j]);
            if (colbest[c] == (tag | bestv[j])) {
                int r = lane * 16 + j;
                act[r] = (float)c;
                atomicOr(&coldone[c >> 5], 1u << (c & 31));
                atomicOr(&rowdone[r >> 5], 1u << (r & 31));
                rowact &= ~(1u << j);
            }
        }
        WAVE_FENCE();          // commits visible before next scan
        if (__ballot(rowact != 0u) == 0ull) break;
    }
    bool leftover = (__ballot((int)(rowact != 0u)) != 0ull);
    bool doFB = leftover || (__ballot((int)exh_l) != 0ull);
    WAVE_FENCE();

    // exact-greedy fallback for exhausted rows (P ~ 1e-5): score keys
    if (doFB) {
        for (int guard = 0; guard < 1200; ++guard) {
            u64 best = 0ull;
            for (int rr = 0; rr < MROWS; ++rr) {
                if ((rowdone[rr >> 5] >> (rr & 31)) & 1u) continue;
                const float* srow = s + (size_t)rr * NCOLS;
                u64 rp = (u64)(MROWS - 1 - rr) << 12;
                for (int c = lane; c < NCOLS; c += 64) {
                    if ((coldone[c >> 5] >> (c & 31)) & 1u) continue;
                    u64 kk = ((u64)fkey(__float_as_uint(srow[c])) << 22) | rp |
                             (u64)(NCOLS - 1 - c);
                    best = umax64(best, kk);
                }
            }
            best = wave_max_u64(best);
            if (best == 0ull) break;
            if (lane == 0) {
                int row = key_row(best), col = key_col(best);
                rowdone[row >> 5] |= 1u << (row & 31);
                coldone[col >> 5] |= 1u << (col & 31);
                act[row] = (float)col;
            }
            WAVE_FENCE();
        }
    }
    WAVE_FENCE();
    for (int i = lane; i < MROWS; i += 64) actions[i] = act[i];
}

extern "C" void kernel_launch(void* const* d_in, const int* in_sizes, int n_in,
                              void* d_out, int out_size, void* d_ws, size_t ws_size,
                              hipStream_t stream) {
    (void)in_sizes; (void)n_in; (void)out_size; (void)ws_size;
    const float* scores = (const float*)d_in[0];
    const int* cont = (const int*)d_in[1];
    const int* prev = (const int*)d_in[2];
    float* out = (float*)d_out;
    float* actions = out;
    float* policy = out + MROWS;

    char* ws = (char*)d_ws;
    float* rowsum = (float*)(ws + 0);            // 1024 f
    unsigned* bitmap = (unsigned*)(ws + 4096);   // 128 u32
    u64* keys8 = (u64*)(ws + 8192);              // 8192 u64

    k_prep<<<MROWS, 256, 0, stream>>>(scores, cont, prev, rowsum, bitmap, keys8);
    k_policy_match<<<MROWS + 1, 256, 0, stream>>>(scores, cont, prev, rowsum,
                                                  bitmap, keys8, policy, actions);
}